// Round 16
// baseline (252.535 us; speedup 1.0000x reference)
//
#include <hip/hip_runtime.h>
#include <cstddef>

#define DSZ 4096

// Permuted diagonal: vp[t*64 + r] = v[i_B(t,r)], where
//   i_B(t,r) = (t&3) + 4r + 256*((t>>2)&3) + 1024*(t>>4)
// so the main kernel's mid-transform multiply reads 16 contiguous float4
// per thread. v[i] = g_mu[i] + softplus(g_rho[i]) * epsilon[i].
__global__ void compute_vperm_kernel(const float* __restrict__ eps,
                                     const float* __restrict__ g_mu,
                                     const float* __restrict__ g_rho,
                                     float* __restrict__ vp) {
    int p = blockIdx.x * blockDim.x + threadIdx.x;
    if (p < DSZ) {
        int t = p >> 6, r = p & 63;
        int i = (t & 3) + 4 * r + 256 * ((t >> 2) & 3) + 1024 * (t >> 4);
        float rho = g_rho[i];
        float sp = fmaxf(rho, 0.0f) + log1pf(expf(-fabsf(rho)));
        vp[p] = g_mu[i] + sp * eps[i];
    }
}

typedef float fv4 __attribute__((ext_vector_type(4)));
__device__ __forceinline__ void nt_store4(float* dst, float a, float b,
                                          float c, float d) {
    fv4 t;
    t.x = a; t.y = b; t.z = c; t.w = d;
    __builtin_nontemporal_store(t, (fv4*)dst);
}

// 6-stage FWHT over 64 registers, compile-time indices only.
#define FWHT64(Y) do {                                                  \
    _Pragma("unroll")                                                   \
    for (int s_ = 1; s_ < 64; s_ <<= 1) {                               \
        _Pragma("unroll")                                               \
        for (int r_ = 0; r_ < 64; ++r_) {                               \
            if ((r_ & s_) == 0) {                                       \
                float a_ = Y[r_];                                       \
                float b_ = Y[r_ | s_];                                  \
                Y[r_]      = a_ + b_;                                   \
                Y[r_ | s_] = a_ - b_;                                   \
            }                                                           \
        }                                                               \
    }                                                                   \
} while (0)

// One ROW per WAVE: 64 regs/thread, zero __syncthreads (exchanges are
// intra-wave; wave-lockstep issue + in-order DS pipe give cross-lane
// ordering; __builtin_amdgcn_wave_barrier() — a zero-instruction compiler
// fence — pins the write-phase/read-phase order against reordering).
// Element-bit layouts (t = lane 0..63, r = reg 0..63):
//   A: i = 4t + (r&3) + 256*(r>>2)                    regs = bits {0,1,8-11}
//   B: i = (t&3) + 4r + 256*((t>>2)&3) + 1024*(t>>4)  regs = bits {2-7}
// Global I/O is in layout A: float4 index t + 64k  -> lane-contiguous.
// LDS swizzle swz(a) = a ^ (((a>>8)&15)<<2), algebraically folded:
//   A-side quad base: (4t ^ 4k) + 256k      (k compile-time)
//   B-side scalar:    Bsw ^ 4r,  Bsw = (t&3) + 260*((t>>2)&3) + 1040*(t>>4)
// Conflicts: A-side uniform-XOR per instr (inherent-min b128); B-side spans
// 32 banks over 64 lanes (2-way = free). Both layouts partition the 4096
// dwords into disjoint per-lane slot sets => all WAR hazards are same-lane.
__global__ __launch_bounds__(256, 2) void whvi_kernel(
        const float* __restrict__ x,
        const float* __restrict__ s1,
        const float* __restrict__ s2,
        const float* __restrict__ vp,
        float* __restrict__ out) {
    __shared__ float lds[4 * DSZ];                 // 64 KB: 16 KB per wave
    const int T  = threadIdx.x;
    const int t  = T & 63;                         // lane
    const int w  = T >> 6;                         // wave in block
    float* lds_w = lds + w * DSZ;

    const int gw = blockIdx.x * 4 + w;             // global wave id
    const int Bsw = (t & 3) + 260 * ((t >> 2) & 3) + 1040 * (t >> 4);

    const float4* s24 = (const float4*)s2;
    const float4* s14 = (const float4*)s1;
    const float4* vp4 = (const float4*)(vp + (size_t)t * 64);

    float y[64];

    #pragma unroll 1                               // keep code = 1 row body
    for (int rr = 0; rr < 2; ++rr) {
        const size_t row = (size_t)gw * 2 + rr;
        const float4* x4 = (const float4*)(x + row * DSZ);

        // ---- load x * s2, layout A (lane-contiguous float4) ----
        #pragma unroll
        for (int k = 0; k < 16; ++k) {
            float4 xv = x4[t + 64 * k];
            float4 sv = s24[t + 64 * k];
            y[4 * k + 0] = xv.x * sv.x;
            y[4 * k + 1] = xv.y * sv.y;
            y[4 * k + 2] = xv.z * sv.z;
            y[4 * k + 3] = xv.w * sv.w;
        }

        FWHT64(y);                                 // transform 1: bits 0,1,8-11

        // ---- exchange A -> B ----
        #pragma unroll
        for (int k = 0; k < 16; ++k)
            *(float4*)&lds_w[((4 * t) ^ (4 * k)) + 256 * k] =
                make_float4(y[4 * k], y[4 * k + 1], y[4 * k + 2], y[4 * k + 3]);
        __builtin_amdgcn_wave_barrier();           // pin write->read order
        #pragma unroll
        for (int r = 0; r < 64; ++r)
            y[r] = lds_w[Bsw ^ (4 * r)];

        FWHT64(y);                                 // transform 1: bits 2-7

        // ---- diagonal v (pre-permuted to B layout) ----
        #pragma unroll
        for (int m = 0; m < 16; ++m) {
            float4 vq = vp4[m];
            y[4 * m + 0] *= vq.x;
            y[4 * m + 1] *= vq.y;
            y[4 * m + 2] *= vq.z;
            y[4 * m + 3] *= vq.w;
        }

        FWHT64(y);                                 // transform 2: bits 2-7

        // ---- exchange B -> A ----
        #pragma unroll
        for (int r = 0; r < 64; ++r)
            lds_w[Bsw ^ (4 * r)] = y[r];
        __builtin_amdgcn_wave_barrier();           // pin write->read order
        #pragma unroll
        for (int k = 0; k < 16; ++k) {
            float4 q = *(const float4*)&lds_w[((4 * t) ^ (4 * k)) + 256 * k];
            y[4 * k + 0] = q.x;
            y[4 * k + 1] = q.y;
            y[4 * k + 2] = q.z;
            y[4 * k + 3] = q.w;
        }

        FWHT64(y);                                 // transform 2: bits 0,1,8-11

        // ---- scale by s1, NT store (lane-contiguous) ----
        float* outrow = out + row * DSZ;
        #pragma unroll
        for (int k = 0; k < 16; ++k) {
            float4 sv = s14[t + 64 * k];
            nt_store4(outrow + 4 * (t + 64 * k),
                      y[4 * k + 0] * sv.x, y[4 * k + 1] * sv.y,
                      y[4 * k + 2] * sv.z, y[4 * k + 3] * sv.w);
        }
        __builtin_amdgcn_wave_barrier();           // row boundary: keep next
    }                                              // A-write after A-read
}

extern "C" void kernel_launch(void* const* d_in, const int* in_sizes, int n_in,
                              void* d_out, int out_size, void* d_ws, size_t ws_size,
                              hipStream_t stream) {
    // setup_inputs order: x, epsilon, s1, s2, g_mu, g_rho
    const float* x     = (const float*)d_in[0];
    const float* eps   = (const float*)d_in[1];
    const float* s1    = (const float*)d_in[2];
    const float* s2    = (const float*)d_in[3];
    const float* g_mu  = (const float*)d_in[4];
    const float* g_rho = (const float*)d_in[5];
    float* out = (float*)d_out;
    float* vp  = (float*)d_ws;   // 16 KB scratch (permuted diagonal)

    compute_vperm_kernel<<<DSZ / 256, 256, 0, stream>>>(eps, g_mu, g_rho, vp);
    // 512 blocks x 4 waves x 2 rows = 4096 rows; 2 blocks/CU (LDS-capped),
    // all blocks co-resident -> single generation, no tail.
    whvi_kernel<<<DSZ / 8, 256, 0, stream>>>(x, s1, s2, vp, out);
}